// Round 3
// baseline (578.917 us; speedup 1.0000x reference)
//
#include <hip/hip_runtime.h>

// SimpleGCN: 2-layer GCN, N=100000 nodes, E=1.6M edges, 128 -> 128(relu) -> 64.
// out = Ahat @ relu(Ahat @ (x@W1) + b1) @ W2 + b2, Ahat = D^-1/2 (A+I) D^-1/2
//
// R3: dis[] folded into GEMM epilogues (gather = pure row-add);
// CSR fill uses cursor=rowptr copy (no per-edge rowptr load); parallel bsum
// scan; dis fused into scan_blocks; int4-vectorized edge passes; 11 launches.

constexpr int BLK = 256;

// ---------------- normalization + CSR build ----------------

__global__ void init_deg_kernel(int* __restrict__ deg, int n) {
    int i = blockIdx.x * BLK + threadIdx.x;
    if (i < n) deg[i] = 0;
}

__global__ void count_deg_kernel(const int* __restrict__ dst, int* __restrict__ deg, int e4) {
    int i = blockIdx.x * BLK + threadIdx.x;
    if (i >= e4) return;
    int4 d = ((const int4*)dst)[i];
    atomicAdd(&deg[d.x], 1);
    atomicAdd(&deg[d.y], 1);
    atomicAdd(&deg[d.z], 1);
    atomicAdd(&deg[d.w], 1);
}

// Per-block exclusive scan of deg -> rowptr, block sums -> bsum, dis = rsqrt(deg+1).
__global__ __launch_bounds__(256)
void scan_blocks_kernel(const int* __restrict__ deg, int* __restrict__ rowptr,
                        int* __restrict__ bsum, float* __restrict__ dis, int n4) {
    __shared__ int ssum[256];
    const int t = threadIdx.x;
    const int i4 = blockIdx.x * 256 + t;
    int4 d = make_int4(0, 0, 0, 0);
    if (i4 < n4) d = ((const int4*)deg)[i4];
    const int s = d.x + d.y + d.z + d.w;
    ssum[t] = s;
    __syncthreads();
    for (int off = 1; off < 256; off <<= 1) {
        int v = (t >= off) ? ssum[t - off] : 0;
        __syncthreads();
        ssum[t] += v;
        __syncthreads();
    }
    const int excl = ssum[t] - s;
    if (i4 < n4) {
        int4 o;
        o.x = excl;
        o.y = o.x + d.x;
        o.z = o.y + d.y;
        o.w = o.z + d.z;
        ((int4*)rowptr)[i4] = o;
        float4 f;
        f.x = rsqrtf((float)(d.x + 1));
        f.y = rsqrtf((float)(d.y + 1));
        f.z = rsqrtf((float)(d.z + 1));
        f.w = rsqrtf((float)(d.w + 1));
        ((float4*)dis)[i4] = f;
    }
    if (t == 255) bsum[blockIdx.x] = ssum[255];
}

// Parallel exclusive scan of bsum[nb] (nb <= 256), one block; rowptr[n] = total.
__global__ __launch_bounds__(256)
void scan_bsum_kernel(int* __restrict__ bsum, int* __restrict__ rowptr, int n, int nb) {
    __shared__ int ssum[256];
    const int t = threadIdx.x;
    int v = (t < nb) ? bsum[t] : 0;
    ssum[t] = v;
    __syncthreads();
    for (int off = 1; off < 256; off <<= 1) {
        int u = (t >= off) ? ssum[t - off] : 0;
        __syncthreads();
        ssum[t] += u;
        __syncthreads();
    }
    if (t < nb) bsum[t] = ssum[t] - v;  // exclusive
    if (t == 255) rowptr[n] = ssum[255];
}

// rowptr += block offset; cursor = rowptr (fill cursor starts at row start).
__global__ void scan_add_kernel(int* __restrict__ rowptr, int* __restrict__ cursor,
                                const int* __restrict__ bsum, int n4) {
    int i4 = blockIdx.x * 256 + threadIdx.x;
    if (i4 >= n4) return;
    int off = bsum[blockIdx.x];
    int4 v = ((int4*)rowptr)[i4];
    v.x += off; v.y += off; v.z += off; v.w += off;
    ((int4*)rowptr)[i4] = v;
    ((int4*)cursor)[i4] = v;
}

__global__ void fill_csr_kernel(const int* __restrict__ src, const int* __restrict__ dst,
                                int* __restrict__ cursor, int* __restrict__ esrc, int e4) {
    int i = blockIdx.x * BLK + threadIdx.x;
    if (i >= e4) return;
    int4 s = ((const int4*)src)[i];
    int4 d = ((const int4*)dst)[i];
    esrc[atomicAdd(&cursor[d.x], 1)] = s.x;
    esrc[atomicAdd(&cursor[d.y], 1)] = s.y;
    esrc[atomicAdd(&cursor[d.z], 1)] = s.z;
    esrc[atomicAdd(&cursor[d.w], 1)] = s.w;
}

// ---------------- dense GEMM (K=128, f32 vector ALU) ----------------
// C[r][:] = dis[r] * (op(A[r][:]) @ B), op = relu if RELU.

__device__ __forceinline__ void fma4(float4& acc, float a, const float4& b) {
    acc.x = fmaf(a, b.x, acc.x);
    acc.y = fmaf(a, b.y, acc.y);
    acc.z = fmaf(a, b.z, acc.z);
    acc.w = fmaf(a, b.w, acc.w);
}

__device__ __forceinline__ void scale4(float4& v, float s) {
    v.x *= s; v.y *= s; v.z *= s; v.w *= s;
}

template <int COLS, int RPB, bool RELU>
__global__ __launch_bounds__(256)
void gemm_k128(const float* __restrict__ A, const float* __restrict__ B,
               const float* __restrict__ dis, float* __restrict__ C, int nrows) {
    constexpr int CG = COLS / 4;
    constexpr int RG = 256 / CG;
    constexpr int RPT = RPB / RG;
    static_assert(RPT == 4, "tile mismatch");

    __shared__ float sB[128 * COLS];
    __shared__ float sA[RPB][128];

    const int t = threadIdx.x;
    const int rowbase = blockIdx.x * RPB;

    const float4* B4 = (const float4*)B;
    float4* sB4 = (float4*)sB;
#pragma unroll
    for (int i = t; i < 128 * COLS / 4; i += 256) sB4[i] = B4[i];

    const float4* A4 = (const float4*)A;
    for (int i = t; i < RPB * 32; i += 256) {
        int r = i >> 5, c4 = i & 31;
        int gr = rowbase + r;
        float4 v = make_float4(0.f, 0.f, 0.f, 0.f);
        if (gr < nrows) v = A4[gr * 32 + c4];
        if (RELU) {
            v.x = fmaxf(v.x, 0.f); v.y = fmaxf(v.y, 0.f);
            v.z = fmaxf(v.z, 0.f); v.w = fmaxf(v.w, 0.f);
        }
        *(float4*)&sA[r][c4 * 4] = v;
    }
    __syncthreads();

    const int tc = t % CG;
    const int tr = (t / CG) * RPT;

    float4 acc0 = make_float4(0.f, 0.f, 0.f, 0.f);
    float4 acc1 = acc0, acc2 = acc0, acc3 = acc0;

#pragma unroll 4
    for (int kq = 0; kq < 32; ++kq) {
        const int k = kq * 4;
        float4 a0 = *(const float4*)&sA[tr + 0][k];
        float4 a1 = *(const float4*)&sA[tr + 1][k];
        float4 a2 = *(const float4*)&sA[tr + 2][k];
        float4 a3 = *(const float4*)&sA[tr + 3][k];
        float4 b0 = sB4[(k + 0) * CG + tc];
        float4 b1 = sB4[(k + 1) * CG + tc];
        float4 b2 = sB4[(k + 2) * CG + tc];
        float4 b3 = sB4[(k + 3) * CG + tc];
        fma4(acc0, a0.x, b0); fma4(acc0, a0.y, b1); fma4(acc0, a0.z, b2); fma4(acc0, a0.w, b3);
        fma4(acc1, a1.x, b0); fma4(acc1, a1.y, b1); fma4(acc1, a1.z, b2); fma4(acc1, a1.w, b3);
        fma4(acc2, a2.x, b0); fma4(acc2, a2.y, b1); fma4(acc2, a2.z, b2); fma4(acc2, a2.w, b3);
        fma4(acc3, a3.x, b0); fma4(acc3, a3.y, b1); fma4(acc3, a3.z, b2); fma4(acc3, a3.w, b3);
    }

    float4* C4 = (float4*)C;
    const int gr = rowbase + tr;
    if (gr + 0 < nrows) { scale4(acc0, dis[gr + 0]); C4[(gr + 0) * CG + tc] = acc0; }
    if (gr + 1 < nrows) { scale4(acc1, dis[gr + 1]); C4[(gr + 1) * CG + tc] = acc1; }
    if (gr + 2 < nrows) { scale4(acc2, dis[gr + 2]); C4[(gr + 2) * CG + tc] = acc2; }
    if (gr + 3 < nrows) { scale4(acc3, dis[gr + 3]); C4[(gr + 3) * CG + tc] = acc3; }
}

// ---------------- CSR gather-aggregate (pre-scaled rows) ----------------
// hs[r][:] = dis[r]*h[r][:] already; out[i][:] = bias + dis[i]*(hs[i][:] + sum_N hs[s][:])

__device__ __forceinline__ void add4(float4& acc, const float4& v) {
    acc.x += v.x; acc.y += v.y; acc.z += v.z; acc.w += v.w;
}

template <int C>
__global__ __launch_bounds__(256)
void gather_add_kernel(const int* __restrict__ rowptr, const int* __restrict__ esrc,
                       const float* __restrict__ dis, const float* __restrict__ hs,
                       const float* __restrict__ bias, float* __restrict__ out, int n) {
    constexpr int L = C / 4;
    const int gid = blockIdx.x * BLK + threadIdx.x;
    const int node = gid / L;
    const int lane = gid % L;
    if (node >= n) return;

    const float4* h4 = (const float4*)hs;
    const int start = rowptr[node];
    const int end = rowptr[node + 1];

    float4 acc = h4[node * L + lane];  // self-loop (pre-scaled by dis[node])

    int k = start;
    for (; k + 3 < end; k += 4) {
        int s0 = esrc[k], s1 = esrc[k + 1], s2 = esrc[k + 2], s3 = esrc[k + 3];
        float4 v0 = h4[s0 * L + lane];
        float4 v1 = h4[s1 * L + lane];
        float4 v2 = h4[s2 * L + lane];
        float4 v3 = h4[s3 * L + lane];
        add4(acc, v0); add4(acc, v1); add4(acc, v2); add4(acc, v3);
    }
    for (; k < end; ++k) add4(acc, h4[esrc[k] * L + lane]);

    const float di = dis[node];
    float4 b = ((const float4*)bias)[lane];
    float4 o;
    o.x = fmaf(di, acc.x, b.x);
    o.y = fmaf(di, acc.y, b.y);
    o.z = fmaf(di, acc.z, b.z);
    o.w = fmaf(di, acc.w, b.w);
    ((float4*)out)[gid] = o;
}

// ---------------- launch ----------------

extern "C" void kernel_launch(void* const* d_in, const int* in_sizes, int n_in,
                              void* d_out, int out_size, void* d_ws, size_t ws_size,
                              hipStream_t stream) {
    const float* x  = (const float*)d_in[0];
    const int*   ei = (const int*)d_in[1];
    const float* W1 = (const float*)d_in[2];
    const float* b1 = (const float*)d_in[3];
    const float* W2 = (const float*)d_in[4];
    const float* b2 = (const float*)d_in[5];
    float* out = (float*)d_out;

    const int n = in_sizes[0] / 128;  // 100000
    const int e = in_sizes[1] / 2;    // 1600000
    const int* src = ei;
    const int* dst = ei + e;

    char* ws = (char*)d_ws;
    float* dis    = (float*)(ws + 0);            // n f32
    int*   deg    = (int*)  (ws + 0x80000);      // n ints
    int*   rowptr = (int*)  (ws + 0x100000);     // n+1 ints
    int*   cursor = (int*)  (ws + 0x180000);     // n ints
    int*   bsum   = (int*)  (ws + 0x200000);     // ~98 ints
    int*   esrc   = (int*)  (ws + 0x210000);     // e ints (6.4 MB)
    float* h      = (float*)(ws + 0x900000);     // n*128 f32 (51.2 MB)
    float* agg1   = (float*)(ws + 0x3A00000);    // n*128 f32 (51.2 MB)
    float* h2     = h;                           // h dead after gather1

    const int nb_n = (n + BLK - 1) / BLK;
    const int e4 = e / 4;                        // e % 4 == 0
    const int nb_e4 = (e4 + BLK - 1) / BLK;
    const int n4 = n / 4;                        // 25000
    const int nb_scan = (n4 + 255) / 256;        // 98 (<= 256 for scan_bsum)

    // normalization + CSR (7 launches)
    init_deg_kernel<<<nb_n, BLK, 0, stream>>>(deg, n);
    count_deg_kernel<<<nb_e4, BLK, 0, stream>>>(dst, deg, e4);
    scan_blocks_kernel<<<nb_scan, 256, 0, stream>>>(deg, rowptr, bsum, dis, n4);
    scan_bsum_kernel<<<1, 256, 0, stream>>>(bsum, rowptr, n, nb_scan);
    scan_add_kernel<<<nb_scan, 256, 0, stream>>>(rowptr, cursor, bsum, n4);
    fill_csr_kernel<<<nb_e4, BLK, 0, stream>>>(src, dst, cursor, esrc, e4);

    // layer 1: hs = dis * (x @ W1); agg1 = gather(hs) + b1
    gemm_k128<128, 32, false><<<(n + 31) / 32, BLK, 0, stream>>>(x, W1, dis, h, n);
    gather_add_kernel<128><<<(n * 32 + BLK - 1) / BLK, BLK, 0, stream>>>(
        rowptr, esrc, dis, h, b1, agg1, n);

    // layer 2: hs2 = dis * (relu(agg1) @ W2); out = gather(hs2) + b2
    gemm_k128<64, 64, true><<<(n + 63) / 64, BLK, 0, stream>>>(agg1, W2, dis, h2, n);
    gather_add_kernel<64><<<(n * 16 + BLK - 1) / BLK, BLK, 0, stream>>>(
        rowptr, esrc, dis, h2, b2, out, n);
}